// Round 7
// baseline (875.028 us; speedup 1.0000x reference)
//
#include <hip/hip_runtime.h>

// Fused SpikingDenseLayer: B=256, T=100, F=K=1024, U=1024.
// One block = one (batch b, 128-wide u-tile), 256 threads.
// v8 = v7 + occupancy unlock + ping-pong W prefetch:
//  * CHUNK=25 (4 scan chunks): Cs = 25x132x4 = 13.2 KB still holds the
//    2x6.4 KB A dbuf. LDS 26.6->13.2 KB lifts the LDS block cap to 12;
//    residency becomes GRID-capped at 8 blocks/CU = 32 waves (v7 measured
//    ~3.2 blocks / 40% occ) -> the 30% latency-stall time gets hidden.
//  * W prefetch is ping-pong (4 k per rolled iter): compute on c while
//    loading n, compute on n while reloading c. Removes v7's 16 v_mov
//    rotation per 2-k iter and halves loop overhead. Prefetch distance
//    ~112 FMA cyc covers L1/L2 latency at full occupancy.
//  * A staging unchanged: global_load_lds (linear [100][16], dbuf,
//    conflict counter 0 since v2). kk loop stays rolled (v4 spill lesson);
//    no __launch_bounds__ min-waves arg (measured cap ~= 256/arg).
//  * tail rows t=96..99 wave-uniform on wave 0; exactly 100 t-rows issued.
// FMA order per output element identical to passing v5/v6/v7 (k-ascending,
// same expression forms) -> currents bitwise identical; scan unchanged.

#define UN 128              // u-columns per block
#define BK 16               // k-slice staged per buffer
#define CS 132              // Cs row stride in floats (128 + 4)
#define CHUNK 25            // t-rows per scan chunk (4 chunks)
#define TMAX 100

__device__ __forceinline__ void gload_lds16(const float* g, float* l) {
    __builtin_amdgcn_global_load_lds(
        (const __attribute__((address_space(1))) void*)g,
        (__attribute__((address_space(3))) void*)l,
        16, 0, 0);
}

__global__ __launch_bounds__(256) void fused_snn(
    const float* __restrict__ x,     // [B,T,F]
    const float* __restrict__ W,     // [F,U]
    const float* __restrict__ bias,  // [U]
    float* __restrict__ spikes,      // [B,T,U]
    float* __restrict__ counts,      // [B,U]
    int B, int T, int F, int U)
{
    // smem: As double-buffer (2 x 1600 floats = 3200) during GEMM; region
    // reused as Cs[25][132] (3300 floats) for the scan. 13.2 KB total.
    __shared__ __align__(16) float smem[CHUNK * CS];
    float* As0 = smem;           // [100][16] linear
    float* As1 = smem + 1600;    // [100][16] linear

    const int tid = threadIdx.x;
    const int tg  = tid >> 4;    // 0..15 -> t = i*16 + tg
    const int ug  = tid & 15;    // 0..15 -> u cols {4ug..} and {64+4ug..}
    const int u0  = blockIdx.x * UN;
    const int b   = blockIdx.y;

    float acc[7][8];
    #pragma unroll
    for (int i = 0; i < 7; i++)
        #pragma unroll
        for (int j = 0; j < 8; j++) acc[i][j] = 0.f;

    const float* xb = x + (size_t)b * T * F;

    // A staging: 100 rows x 64 B = 400 16-B slots; slot s = row s>>2,
    // byte (s&3)*16; LDS dest = slot*16 (linear, as global_load_lds needs).
    const float* ga0 = xb + (size_t)(tid >> 2) * F + (tid & 3) * 4;
    const float* ga1 = xb + (size_t)(64 + (tid >> 2)) * F + (tid & 3) * 4;
    const int la0 = tid * 4;
    const int la1 = (256 + tid) * 4;
    const bool a1on = (tid < 144);           // slots 256..399
    const bool w0   = (tid < 64);            // wave 0 owns tail rows 96..99

    // Per-lane W base: row k is wlane + k*U; u-halves at +0 and +64.
    const float* wlane = W + u0 + 4 * ug;

#define STAGE(buf, kof)                                   \
    do {                                                  \
        gload_lds16(ga0 + (kof), (buf) + la0);            \
        if (a1on) gload_lds16(ga1 + (kof), (buf) + la1);  \
    } while (0)

    // 112 FMAs for k-pair at LDS offset kk using W regs B0..B3.
#define FMABLK(ap, kk, B0, B1, B2, B3)                                     \
    do {                                                                   \
        _Pragma("unroll")                                                  \
        for (int i = 0; i < 6; i++) {                                      \
            float2 a = *(const float2*)((ap) + i * 256 + (kk));            \
            acc[i][0] += a.x * B0.x;  acc[i][1] += a.x * B0.y;             \
            acc[i][2] += a.x * B0.z;  acc[i][3] += a.x * B0.w;             \
            acc[i][4] += a.x * B1.x;  acc[i][5] += a.x * B1.y;             \
            acc[i][6] += a.x * B1.z;  acc[i][7] += a.x * B1.w;             \
            acc[i][0] += a.y * B2.x;  acc[i][1] += a.y * B2.y;             \
            acc[i][2] += a.y * B2.z;  acc[i][3] += a.y * B2.w;             \
            acc[i][4] += a.y * B3.x;  acc[i][5] += a.y * B3.y;             \
            acc[i][6] += a.y * B3.z;  acc[i][7] += a.y * B3.w;             \
        }                                                                  \
        if (w0) {  /* tail rows t=96..99, wave-uniform, all lanes */       \
            float2 a = *(const float2*)((ap) + 6 * 256 + (kk));            \
            acc[6][0] += a.x * B0.x;  acc[6][1] += a.x * B0.y;             \
            acc[6][2] += a.x * B0.z;  acc[6][3] += a.x * B0.w;             \
            acc[6][4] += a.x * B1.x;  acc[6][5] += a.x * B1.y;             \
            acc[6][6] += a.x * B1.z;  acc[6][7] += a.x * B1.w;             \
            acc[6][0] += a.y * B2.x;  acc[6][1] += a.y * B2.y;             \
            acc[6][2] += a.y * B2.z;  acc[6][3] += a.y * B2.w;             \
            acc[6][4] += a.y * B3.x;  acc[6][5] += a.y * B3.y;             \
            acc[6][6] += a.y * B3.z;  acc[6][7] += a.y * B3.w;             \
        }                                                                  \
    } while (0)

    // Ping-pong: entry invariant c0..c3 = W rows (k0b+kk, k0b+kk+1).
#define COMPUTE(buf, k0b)                                                  \
    do {                                                                   \
        const float* ap = (buf) + tg * 16;                                 \
        _Pragma("unroll 1")                                                \
        for (int kk = 0; kk < BK; kk += 4) {                               \
            {   const int kg = (k0b) + kk + 2;                             \
                const int kn = (kg < F) ? kg : 0;                          \
                const float* wn = wlane + (size_t)kn * U;                  \
                n0 = *(const float4*)(wn);                                 \
                n1 = *(const float4*)(wn + 64);                            \
                n2 = *(const float4*)(wn + U);                             \
                n3 = *(const float4*)(wn + U + 64);                        \
            }                                                              \
            FMABLK(ap, kk, c0, c1, c2, c3);                                \
            {   const int kg = (k0b) + kk + 4;                             \
                const int kn = (kg < F) ? kg : 0;                          \
                const float* wn = wlane + (size_t)kn * U;                  \
                c0 = *(const float4*)(wn);                                 \
                c1 = *(const float4*)(wn + 64);                            \
                c2 = *(const float4*)(wn + U);                             \
                c3 = *(const float4*)(wn + U + 64);                        \
            }                                                              \
            FMABLK(ap, kk + 2, n0, n1, n2, n3);                            \
        }                                                                  \
    } while (0)

    float4 c0, c1, c2, c3, n0, n1, n2, n3;

    // prologue: fill buffer 0 and preload W rows k=0,1
    STAGE(As0, 0);
    c0 = *(const float4*)(wlane);
    c1 = *(const float4*)(wlane + 64);
    c2 = *(const float4*)(wlane + U);
    c3 = *(const float4*)(wlane + U + 64);
    __syncthreads();   // auto vmcnt(0): As0 visible

    #pragma unroll 1
    for (int k0 = 0; k0 < F; k0 += 2 * BK) {
        STAGE(As1, k0 + BK);                  // async: next tile into As1
        COMPUTE(As0, k0);
        __syncthreads();                      // drains STAGE + readers done
        if (k0 + 2 * BK < F) STAGE(As0, k0 + 2 * BK);
        COMPUTE(As1, k0 + BK);
        __syncthreads();
    }

#undef STAGE
#undef COMPUTE
#undef FMABLK

    // ---- bias ----
    float bb[8];
    {
        float4 bv0 = *(const float4*)(bias + u0 + 4 * ug);
        float4 bv1 = *(const float4*)(bias + u0 + 64 + 4 * ug);
        bb[0] = bv0.x; bb[1] = bv0.y; bb[2] = bv0.z; bb[3] = bv0.w;
        bb[4] = bv1.x; bb[5] = bv1.y; bb[6] = bv1.z; bb[7] = bv1.w;
    }

    // ---- chunked dump + LIF scan (4 x 25 t-rows) ----
    float v = 0.f, cnt = 0.f;
    float* sp = spikes + (size_t)b * T * U + u0 + tid;   // used when tid<UN

    #pragma unroll
    for (int c = 0; c < 4; c++) {
        #pragma unroll
        for (int i = 0; i < 7; i++) {
            const int t = i * 16 + tg;
            if (t >= c * CHUNK && t < c * CHUNK + CHUNK && t < TMAX) {
                const int r = t - c * CHUNK;
                float4 d0, d1;
                d0.x = acc[i][0] + bb[0]; d0.y = acc[i][1] + bb[1];
                d0.z = acc[i][2] + bb[2]; d0.w = acc[i][3] + bb[3];
                d1.x = acc[i][4] + bb[4]; d1.y = acc[i][5] + bb[5];
                d1.z = acc[i][6] + bb[6]; d1.w = acc[i][7] + bb[7];
                *(float4*)(smem + r * CS + 4 * ug)      = d0;
                *(float4*)(smem + r * CS + 64 + 4 * ug) = d1;
            }
        }
        __syncthreads();
        if (tid < UN) {
#pragma clang fp contract(off)
            // rounding matches numpy elementwise exactly:
            // v = 0.25*v + round(0.75*c); spike = v > 1.0; v -= spike.
            for (int r = 0; r < CHUNK; r++) {
                float cval = smem[r * CS + tid];
                v = 0.25f * v + 0.75f * cval;
                float s = (v > 1.0f) ? 1.0f : 0.0f;
                v -= s;
                cnt += s;
                sp[(size_t)(c * CHUNK + r) * U] = s;
            }
        }
        __syncthreads();   // scan done before next chunk overwrites Cs
    }
    if (tid < UN) counts[(size_t)b * U + u0 + tid] = cnt;
}

extern "C" void kernel_launch(void* const* d_in, const int* in_sizes, int n_in,
                              void* d_out, int out_size, void* d_ws, size_t ws_size,
                              hipStream_t stream) {
    const float* x    = (const float*)d_in[0];  // [B,T,F]
    const float* kern = (const float*)d_in[1];  // [F,U]
    const float* bias = (const float*)d_in[2];  // [U]
    float* out = (float*)d_out;

    const int U = in_sizes[2];                 // 1024
    const int F = in_sizes[1] / U;             // 1024
    const int R = in_sizes[0] / F;             // B*T = 25600
    const int B = out_size / U - R;            // 256
    const int T = R / B;                       // 100

    float* spikes = out;
    float* counts = out + (size_t)R * U;

    dim3 grid(U / UN, B);                      // (8, 256)
    fused_snn<<<grid, 256, 0, stream>>>(x, kern, bias, spikes, counts,
                                        B, T, F, U);
}